// Round 1
// baseline (250.470 us; speedup 1.0000x reference)
//
#include <hip/hip_runtime.h>

// LinearAttention: B=8, N=16384 (128x128), C=96, H=4, d=24
// K1: k = elu(x@Wk^T+bk)+1  -> atomically accumulate k_sum and kv = sum k_rope (x) v / n
// K2: q = elu(x@Wq^T+bq)+1  -> rope, z, out = q_rope@kv*z + depthwise3x3(x) + bias

#define ROWP 104            // LDS row pitch in bf16 elems (208B: 16B-aligned, ~2-way banks)
#define NLINE 16384
#define CCH 96

typedef __attribute__((ext_vector_type(4))) float f32x4;
typedef __attribute__((ext_vector_type(8))) short bf16x8;

__device__ __forceinline__ unsigned short f2bf(float f) {
  unsigned int u = __float_as_uint(f);
  u += 0x7FFFu + ((u >> 16) & 1u);          // RNE
  return (unsigned short)(u >> 16);
}
__device__ __forceinline__ float bf2f(unsigned short h) {
  return __uint_as_float(((unsigned int)h) << 16);
}
__device__ __forceinline__ void store_bf4(unsigned short* dst, f32x4 v) {
  unsigned long long pk = (unsigned long long)f2bf(v.x)
    | ((unsigned long long)f2bf(v.y) << 16)
    | ((unsigned long long)f2bf(v.z) << 32)
    | ((unsigned long long)f2bf(v.w) << 48);
  *(unsigned long long*)dst = pk;
}

// theta_j = 10000^(-j/48) = 2^(-j * log2(10000)/48)
#define THETA_COEF 0.2768273412406135f

// ---------------------------------------------------------------- kernel 1
__global__ __launch_bounds__(256) void la_k1(
    const float* __restrict__ x, const float* __restrict__ qkw,
    const float* __restrict__ qkb, float* __restrict__ kv_g,
    float* __restrict__ ksum_g)
{
  const int tid  = threadIdx.x;
  const int b    = blockIdx.x >> 7;
  const int tile = blockIdx.x & 127;

  __shared__ alignas(16) unsigned short xs[128 * ROWP];  // x tile (= v), bf16
  __shared__ alignas(16) unsigned short wk[96 * ROWP];   // Wk, bf16
  __shared__ alignas(16) unsigned short ks[128 * ROWP];  // k then k_rope, bf16
  __shared__ float biask[96];
  __shared__ float theta_s[48];
  __shared__ float ksum_s[96];

  if (tid < 96) { biask[tid] = qkb[96 + tid]; ksum_s[tid] = 0.0f; }
  if (tid < 48) theta_s[tid] = exp2f(-THETA_COEF * (float)tid);

  // stage x tile (128 rows x 96 f32 -> bf16)
  const float* xb = x + ((size_t)b * NLINE + (size_t)tile * 128) * CCH;
  for (int i = tid; i < 3072; i += 256) {
    int r = i / 24, c4 = i % 24;
    store_bf4(&xs[r * ROWP + c4 * 4], ((const f32x4*)xb)[i]);
  }
  // stage Wk (rows 96..191 of qk_w)
  const float* wkg = qkw + 96 * 96;
  for (int i = tid; i < 2304; i += 256) {
    int r = i / 24, c4 = i % 24;
    store_bf4(&wk[r * ROWP + c4 * 4], ((const f32x4*)wkg)[i]);
  }
  __syncthreads();

  const int wave = tid >> 6;
  const int lane = tid & 63;
  const int lr   = lane & 15;
  const int q4   = lane >> 4;

  // k = x @ Wk^T : wave handles rows [wave*32, wave*32+32), 6 n-tiles, 3 k-steps
  f32x4 acc[2][6];
#pragma unroll
  for (int mt = 0; mt < 2; ++mt)
#pragma unroll
    for (int nt = 0; nt < 6; ++nt) acc[mt][nt] = (f32x4){0.f, 0.f, 0.f, 0.f};

#pragma unroll
  for (int kk = 0; kk < 3; ++kk) {
    const int koff = kk * 32 + q4 * 8;
    bf16x8 a0 = *(const bf16x8*)&xs[(wave * 32 + lr) * ROWP + koff];
    bf16x8 a1 = *(const bf16x8*)&xs[(wave * 32 + 16 + lr) * ROWP + koff];
#pragma unroll
    for (int nt = 0; nt < 6; ++nt) {
      bf16x8 bf = *(const bf16x8*)&wk[(nt * 16 + lr) * ROWP + koff];
      acc[0][nt] = __builtin_amdgcn_mfma_f32_16x16x32_bf16(a0, bf, acc[0][nt], 0, 0, 0);
      acc[1][nt] = __builtin_amdgcn_mfma_f32_16x16x32_bf16(a1, bf, acc[1][nt], 0, 0, 0);
    }
  }

  // epilogue: +bias, elu+1, col-sum, store raw k to LDS
#pragma unroll
  for (int nt = 0; nt < 6; ++nt) {
    const int col = nt * 16 + lr;
    const float bias = biask[col];
    float csum = 0.0f;
#pragma unroll
    for (int mt = 0; mt < 2; ++mt) {
#pragma unroll
      for (int rg = 0; rg < 4; ++rg) {
        int row = wave * 32 + mt * 16 + q4 * 4 + rg;
        float v = acc[mt][nt][rg] + bias;
        v = (v > 0.0f) ? (v + 1.0f) : __expf(v);   // elu(v)+1
        csum += v;
        ks[row * ROWP + col] = f2bf(v);
      }
    }
    atomicAdd(&ksum_s[col], csum);
  }
  __syncthreads();

  if (tid < 96) atomicAdd(&ksum_g[b * 96 + tid], ksum_s[tid]);

  // rope in-place on ks (w_idx = r since tile is 128-aligned)
  for (int i = tid; i < 6144; i += 256) {
    int r = i & 127, j = i >> 7;
    unsigned int* p = (unsigned int*)&ks[r * ROWP + 2 * j];
    unsigned int u = *p;
    float re = bf2f((unsigned short)(u & 0xFFFFu));
    float im = bf2f((unsigned short)(u >> 16));
    float sn, cn;
    __sincosf((float)r * theta_s[j], &sn, &cn);
    float ore = re * cn - im * sn;
    float oim = re * sn + im * cn;
    *p = (unsigned int)f2bf(ore) | ((unsigned int)f2bf(oim) << 16);
  }
  __syncthreads();

  // kv partial: per wave = head h: D[d][e] = sum_r k_rope[r][24h+d] * v[r][24h+e]
  const int h = wave;
  f32x4 kvacc[2][2];
#pragma unroll
  for (int mt = 0; mt < 2; ++mt)
#pragma unroll
    for (int nt = 0; nt < 2; ++nt) kvacc[mt][nt] = (f32x4){0.f, 0.f, 0.f, 0.f};

  for (int kk = 0; kk < 4; ++kk) {          // K = 128 rows, 4 steps of 32
    const int rbase = kk * 32 + q4 * 8;
    bf16x8 afr[2], bfr[2];
#pragma unroll
    for (int mt = 0; mt < 2; ++mt) {
      int c = 24 * h + mt * 16 + lr; if (c > 95) c = 95;  // clamp; garbage rows discarded
#pragma unroll
      for (int j = 0; j < 8; ++j) afr[mt][j] = (short)ks[(rbase + j) * ROWP + c];
    }
#pragma unroll
    for (int nt = 0; nt < 2; ++nt) {
      int c = 24 * h + nt * 16 + lr; if (c > 95) c = 95;
#pragma unroll
      for (int j = 0; j < 8; ++j) bfr[nt][j] = (short)xs[(rbase + j) * ROWP + c];
    }
#pragma unroll
    for (int mt = 0; mt < 2; ++mt)
#pragma unroll
      for (int nt = 0; nt < 2; ++nt)
        kvacc[mt][nt] = __builtin_amdgcn_mfma_f32_16x16x32_bf16(afr[mt], bfr[nt], kvacc[mt][nt], 0, 0, 0);
  }

  const float inv_n = 1.0f / 16384.0f;
  float* kvb = kv_g + ((size_t)b * 4 + h) * 576;
#pragma unroll
  for (int mt = 0; mt < 2; ++mt) {
#pragma unroll
    for (int rg = 0; rg < 4; ++rg) {
      int d = mt * 16 + q4 * 4 + rg;
      if (d < 24) {
#pragma unroll
        for (int nt = 0; nt < 2; ++nt) {
          int e = nt * 16 + lr;
          if (e < 24) atomicAdd(&kvb[d * 24 + e], kvacc[mt][nt][rg] * inv_n);
        }
      }
    }
  }
}

// ---------------------------------------------------------------- kernel 2
__global__ __launch_bounds__(256) void la_k2(
    const float* __restrict__ x, const float* __restrict__ qkw,
    const float* __restrict__ qkb, const float* __restrict__ lepe_w,
    const float* __restrict__ lepe_b, const float* __restrict__ kv_g,
    const float* __restrict__ ksum_g, float* __restrict__ out)
{
  const int tid = threadIdx.x;
  // XCD swizzle: batch = blockIdx%8 (one batch per XCD), y sequential -> L2 halo reuse
  const int b = blockIdx.x & 7;
  const int y = blockIdx.x >> 3;

  __shared__ alignas(16) unsigned short xl[3 * 128 * ROWP]; // 3 image lines, bf16
  __shared__ alignas(16) unsigned short wq[96 * ROWP];
  __shared__ alignas(16) unsigned short qs[128 * ROWP];
  __shared__ float biasq[96];
  __shared__ float theta_s[48];

  if (tid < 96) biasq[tid] = qkb[tid];
  if (tid < 48) theta_s[tid] = exp2f(-THETA_COEF * (float)tid);

  const float* xb = x + (size_t)b * NLINE * CCH;
  for (int ln = 0; ln < 3; ++ln) {
    int yy = y + ln - 1;
    bool ok = (yy >= 0) && (yy < 128);
    const f32x4* src = (const f32x4*)(xb + (size_t)(ok ? yy : 0) * 128 * CCH);
    for (int i = tid; i < 3072; i += 256) {
      f32x4 v = ok ? src[i] : (f32x4){0.f, 0.f, 0.f, 0.f};
      int r = i / 24, c4 = i % 24;
      store_bf4(&xl[ln * 128 * ROWP + r * ROWP + c4 * 4], v);
    }
  }
  for (int i = tid; i < 2304; i += 256) {
    int r = i / 24, c4 = i % 24;
    store_bf4(&wq[r * ROWP + c4 * 4], ((const f32x4*)qkw)[i]);
  }
  __syncthreads();

  const int wave = tid >> 6;
  const int lane = tid & 63;
  const int lr   = lane & 15;
  const int q4   = lane >> 4;
  const unsigned short* xc = xl + 128 * ROWP;   // center line

  f32x4 acc[2][6];
#pragma unroll
  for (int mt = 0; mt < 2; ++mt)
#pragma unroll
    for (int nt = 0; nt < 6; ++nt) acc[mt][nt] = (f32x4){0.f, 0.f, 0.f, 0.f};

#pragma unroll
  for (int kk = 0; kk < 3; ++kk) {
    const int koff = kk * 32 + q4 * 8;
    bf16x8 a0 = *(const bf16x8*)&xc[(wave * 32 + lr) * ROWP + koff];
    bf16x8 a1 = *(const bf16x8*)&xc[(wave * 32 + 16 + lr) * ROWP + koff];
#pragma unroll
    for (int nt = 0; nt < 6; ++nt) {
      bf16x8 bf = *(const bf16x8*)&wq[(nt * 16 + lr) * ROWP + koff];
      acc[0][nt] = __builtin_amdgcn_mfma_f32_16x16x32_bf16(a0, bf, acc[0][nt], 0, 0, 0);
      acc[1][nt] = __builtin_amdgcn_mfma_f32_16x16x32_bf16(a1, bf, acc[1][nt], 0, 0, 0);
    }
  }
#pragma unroll
  for (int nt = 0; nt < 6; ++nt) {
    const int col = nt * 16 + lr;
    const float bias = biasq[col];
#pragma unroll
    for (int mt = 0; mt < 2; ++mt) {
#pragma unroll
      for (int rg = 0; rg < 4; ++rg) {
        int row = wave * 32 + mt * 16 + q4 * 4 + rg;
        float v = acc[mt][nt][rg] + bias;
        v = (v > 0.0f) ? (v + 1.0f) : __expf(v);
        qs[row * ROWP + col] = f2bf(v);
      }
    }
  }
  __syncthreads();

  // epilogue: per (r, h) pair; h wave-uniform -> scalar loads for kv / k_mean / lepe_w
  const float inv_n = 1.0f / 16384.0f;
  for (int pass = 0; pass < 2; ++pass) {
    int p = tid + pass * 256;
    int r = p & 127;
    int hu = __builtin_amdgcn_readfirstlane(p >> 7);

    float qv[24];
    const unsigned int* qrow = (const unsigned int*)&qs[r * ROWP + 24 * hu];
#pragma unroll
    for (int t = 0; t < 12; ++t) {
      unsigned int u = qrow[t];
      qv[2 * t]     = bf2f((unsigned short)(u & 0xFFFFu));
      qv[2 * t + 1] = bf2f((unsigned short)(u >> 16));
    }

    const float* km = ksum_g + b * 96 + 24 * hu;
    float dot = 0.0f;
#pragma unroll
    for (int d2 = 0; d2 < 24; ++d2) dot += qv[d2] * km[d2];
    float z = 1.0f / (dot * inv_n + 1e-6f);

    float qr[24];
#pragma unroll
    for (int jj = 0; jj < 12; ++jj) {
      float sn, cn;
      __sincosf((float)r * theta_s[12 * hu + jj], &sn, &cn);
      float re = qv[2 * jj], im = qv[2 * jj + 1];
      qr[2 * jj]     = re * cn - im * sn;
      qr[2 * jj + 1] = re * sn + im * cn;
    }

    const float* kvh = kv_g + ((size_t)b * 4 + hu) * 576;
    float res[24];
#pragma unroll
    for (int e = 0; e < 24; ++e) res[e] = 0.0f;
    for (int d2 = 0; d2 < 24; ++d2) {
      float qd = qr[d2];
#pragma unroll
      for (int e = 0; e < 24; ++e) res[e] += qd * kvh[d2 * 24 + e];
    }
    const float* lb = lepe_b + 24 * hu;
#pragma unroll
    for (int e = 0; e < 24; ++e) res[e] = res[e] * z + lb[e];

    // depthwise 3x3 conv on x (lines already zero-filled for OOB y)
    const float* lw = lepe_w + (size_t)(24 * hu) * 9;
#pragma unroll
    for (int dy = 0; dy < 3; ++dy) {
#pragma unroll
      for (int dx = 0; dx < 3; ++dx) {
        int xc2 = r + dx - 1;
        if (xc2 < 0 || xc2 > 127) continue;
        const unsigned int* xrow =
            (const unsigned int*)&xl[dy * 128 * ROWP + xc2 * ROWP + 24 * hu];
        int tap = dy * 3 + dx;
#pragma unroll
        for (int t = 0; t < 12; ++t) {
          unsigned int u = xrow[t];
          res[2 * t]     += lw[(2 * t) * 9 + tap]     * bf2f((unsigned short)(u & 0xFFFFu));
          res[2 * t + 1] += lw[(2 * t + 1) * 9 + tap] * bf2f((unsigned short)(u >> 16));
        }
      }
    }

    float* op = out + ((size_t)b * NLINE + (size_t)y * 128 + r) * CCH + 24 * hu;
#pragma unroll
    for (int t = 0; t < 6; ++t) {
      f32x4 v4 = { res[4 * t], res[4 * t + 1], res[4 * t + 2], res[4 * t + 3] };
      ((f32x4*)op)[t] = v4;
    }
  }
}

// ---------------------------------------------------------------- launch
extern "C" void kernel_launch(void* const* d_in, const int* in_sizes, int n_in,
                              void* d_out, int out_size, void* d_ws, size_t ws_size,
                              hipStream_t stream) {
  const float* x      = (const float*)d_in[0];
  const float* qkw    = (const float*)d_in[1];
  const float* qkb    = (const float*)d_in[2];
  const float* lepe_w = (const float*)d_in[3];
  const float* lepe_b = (const float*)d_in[4];
  float* out = (float*)d_out;

  float* kv_g   = (float*)d_ws;          // 8*4*24*24 = 18432 floats
  float* ksum_g = kv_g + 18432;          // 8*96      =   768 floats

  hipMemsetAsync(d_ws, 0, (18432 + 768) * sizeof(float), stream);
  la_k1<<<dim3(1024), dim3(256), 0, stream>>>(x, qkw, qkb, kv_g, ksum_g);
  la_k2<<<dim3(1024), dim3(256), 0, stream>>>(x, qkw, qkb, lepe_w, lepe_b, kv_g, ksum_g, out);
}

// Round 2
// 218.076 us; speedup vs baseline: 1.1485x; 1.1485x over previous
//
#include <hip/hip_runtime.h>

// LinearAttention: B=8, N=16384 (128x128), C=96, H=4, d=24
// prep: qk_w (192x96 f32) -> bf16 in ws
// K1: full 192-col GEMM per 128-row tile. q -> elu+1 -> f32 in-place into d_out.
//     k -> elu+1 -> ksum atomics; rope in LDS; kv = K_rope^T V via MFMA -> atomics.
// K2: streaming epilogue: read q from d_out, rope/z/kv-matvec + f32 conv, write out in-place.

#define NLINE 16384
#define CCH 96
#define XSP 104                     // xs pitch (bf16 elems): 208B rows, 2-way banks
#define THETA_COEF 0.2768273412406135f  // log2(10000)/48

typedef __attribute__((ext_vector_type(4))) float f32x4;
typedef __attribute__((ext_vector_type(8))) short bf16x8;

__device__ __forceinline__ unsigned short f2bf(float f) {
  unsigned int u = __float_as_uint(f);
  u += 0x7FFFu + ((u >> 16) & 1u);          // RNE
  return (unsigned short)(u >> 16);
}
__device__ __forceinline__ float bf2f(unsigned short h) {
  return __uint_as_float(((unsigned int)h) << 16);
}
__device__ __forceinline__ void store_bf4(unsigned short* dst, f32x4 v) {
  unsigned long long pk = (unsigned long long)f2bf(v.x)
    | ((unsigned long long)f2bf(v.y) << 16)
    | ((unsigned long long)f2bf(v.z) << 32)
    | ((unsigned long long)f2bf(v.w) << 48);
  *(unsigned long long*)dst = pk;
}
// swizzled k-buffer index: pitch 96, group (c>>3) XOR'd with (r&7).
// 2-way bank conflicts on row reads (free); kv column reads have r&7 == j.
__device__ __forceinline__ int swz(int r, int c) {
  return r * 96 + (((c >> 3) ^ (r & 7)) << 3) + (c & 7);
}

// ---------------------------------------------------------------- prep
__global__ void prep_w(const float* __restrict__ qkw, unsigned short* __restrict__ wbf) {
  int i = blockIdx.x * 256 + threadIdx.x;
  if (i < 192 * 96) wbf[i] = f2bf(qkw[i]);
}

// ---------------------------------------------------------------- kernel 1
__global__ __launch_bounds__(256) void la_k1(
    const float* __restrict__ x, const unsigned short* __restrict__ wbf,
    const float* __restrict__ qkb, float* __restrict__ qout,
    float* __restrict__ kv_g, float* __restrict__ ksum_g)
{
  const int tid  = threadIdx.x;
  const int b    = blockIdx.x >> 7;
  const int tile = blockIdx.x & 127;

  __shared__ alignas(16) unsigned short xs[128 * XSP];   // 26.6 KB, bf16 (= v)
  __shared__ alignas(16) unsigned short ks[128 * 96];    // 24 KB, swizzled bf16
  __shared__ float theta_s[48];
  __shared__ float ksum_s[96];
  __shared__ float biasq[96], biask[96];

  if (tid < 96) { biasq[tid] = qkb[tid]; biask[tid] = qkb[96 + tid]; ksum_s[tid] = 0.0f; }
  if (tid < 48) theta_s[tid] = exp2f(-THETA_COEF * (float)tid);

  const float* xb = x + ((size_t)b * NLINE + (size_t)tile * 128) * CCH;
  for (int i = tid; i < 3072; i += 256) {
    int r = i / 24, c4 = i % 24;
    store_bf4(&xs[r * XSP + c4 * 4], ((const f32x4*)xb)[i]);
  }
  __syncthreads();

  const int wave = tid >> 6;
  const int lane = tid & 63;
  const int lr   = lane & 15;
  const int q4   = lane >> 4;
  const int row0 = wave * 32;
  const size_t orow = (size_t)b * NLINE + (size_t)tile * 128;

  // ---- half 0: q (W rows 0..95) -> global f32; half 1: k -> LDS ----
#pragma unroll
  for (int half = 0; half < 2; ++half) {
    const unsigned short* wh = wbf + half * 96 * 96;
    f32x4 acc[2][6];
#pragma unroll
    for (int mt = 0; mt < 2; ++mt)
#pragma unroll
      for (int nt = 0; nt < 6; ++nt) acc[mt][nt] = (f32x4){0.f, 0.f, 0.f, 0.f};

#pragma unroll
    for (int kk = 0; kk < 3; ++kk) {
      const int koff = kk * 32 + q4 * 8;
      bf16x8 a0 = *(const bf16x8*)&xs[(row0 + lr) * XSP + koff];
      bf16x8 a1 = *(const bf16x8*)&xs[(row0 + 16 + lr) * XSP + koff];
#pragma unroll
      for (int nt = 0; nt < 6; ++nt) {
        bf16x8 bf = *(const bf16x8*)&wh[(nt * 16 + lr) * 96 + koff];
        acc[0][nt] = __builtin_amdgcn_mfma_f32_16x16x32_bf16(a0, bf, acc[0][nt], 0, 0, 0);
        acc[1][nt] = __builtin_amdgcn_mfma_f32_16x16x32_bf16(a1, bf, acc[1][nt], 0, 0, 0);
      }
    }

    if (half == 0) {
#pragma unroll
      for (int nt = 0; nt < 6; ++nt) {
        const int col = nt * 16 + lr;
        const float bias = biasq[col];
#pragma unroll
        for (int mt = 0; mt < 2; ++mt)
#pragma unroll
          for (int rg = 0; rg < 4; ++rg) {
            int row = row0 + mt * 16 + q4 * 4 + rg;
            float v = acc[mt][nt][rg] + bias;
            v = (v > 0.0f) ? (v + 1.0f) : __expf(v);
            qout[(orow + row) * CCH + col] = v;
          }
      }
    } else {
#pragma unroll
      for (int nt = 0; nt < 6; ++nt) {
        const int col = nt * 16 + lr;
        const float bias = biask[col];
        float csum = 0.0f;
#pragma unroll
        for (int mt = 0; mt < 2; ++mt)
#pragma unroll
          for (int rg = 0; rg < 4; ++rg) {
            int row = row0 + mt * 16 + q4 * 4 + rg;
            float v = acc[mt][nt][rg] + bias;
            v = (v > 0.0f) ? (v + 1.0f) : __expf(v);
            csum += v;
            ks[swz(row, col)] = f2bf(v);
          }
        atomicAdd(&ksum_s[col], csum);
      }
    }
  }
  __syncthreads();

  if (tid < 96) atomicAdd(&ksum_g[b * 96 + tid], ksum_s[tid]);

  // rope in place on ks (angle index = row within tile = token % 128)
  for (int i = tid; i < 6144; i += 256) {
    int r = i & 127, j = i >> 7;
    unsigned int* p = (unsigned int*)&ks[r * 96 + (((j >> 2) ^ (r & 7)) << 3) + ((j & 3) << 1)];
    unsigned int u = *p;
    float re = bf2f((unsigned short)(u & 0xFFFFu));
    float im = bf2f((unsigned short)(u >> 16));
    float sn, cn;
    __sincosf((float)r * theta_s[j], &sn, &cn);
    float ore = re * cn - im * sn;
    float oim = re * sn + im * cn;
    *p = (unsigned int)f2bf(ore) | ((unsigned int)f2bf(oim) << 16);
  }
  __syncthreads();

  // kv partial: wave = head h: D[d][e] = sum_r k_rope[r][24h+d] * v[r][24h+e]
  const int h = wave;
  f32x4 kvacc[2][2];
#pragma unroll
  for (int mt = 0; mt < 2; ++mt)
#pragma unroll
    for (int nt = 0; nt < 2; ++nt) kvacc[mt][nt] = (f32x4){0.f, 0.f, 0.f, 0.f};

#pragma unroll
  for (int kk = 0; kk < 4; ++kk) {
    const int rbase = kk * 32 + q4 * 8;     // rbase % 8 == 0 -> (rbase+j)&7 == j
    bf16x8 afr[2], bfr[2];
#pragma unroll
    for (int mt = 0; mt < 2; ++mt) {
      int c = 24 * h + mt * 16 + lr; if (c > 95) c = 95;  // clamped rows filtered below
      const int cg = c >> 3, c7 = c & 7, base = rbase * 96 + c7;
#pragma unroll
      for (int j = 0; j < 8; ++j) afr[mt][j] = (short)ks[base + j * 96 + ((cg ^ j) << 3)];
    }
#pragma unroll
    for (int nt = 0; nt < 2; ++nt) {
      int c = 24 * h + nt * 16 + lr; if (c > 95) c = 95;
#pragma unroll
      for (int j = 0; j < 8; ++j) bfr[nt][j] = (short)xs[(rbase + j) * XSP + c];
    }
#pragma unroll
    for (int mt = 0; mt < 2; ++mt)
#pragma unroll
      for (int nt = 0; nt < 2; ++nt)
        kvacc[mt][nt] = __builtin_amdgcn_mfma_f32_16x16x32_bf16(afr[mt], bfr[nt], kvacc[mt][nt], 0, 0, 0);
  }

  const float inv_n = 1.0f / 16384.0f;
  float* kvb = kv_g + ((size_t)b * 4 + h) * 576;
#pragma unroll
  for (int mt = 0; mt < 2; ++mt) {
#pragma unroll
    for (int rg = 0; rg < 4; ++rg) {
      int d = mt * 16 + q4 * 4 + rg;
      if (d < 24) {
#pragma unroll
        for (int nt = 0; nt < 2; ++nt) {
          int e = nt * 16 + lr;
          if (e < 24) atomicAdd(&kvb[d * 24 + e], kvacc[mt][nt][rg] * inv_n);
        }
      }
    }
  }
}

// ---------------------------------------------------------------- kernel 2
__global__ __launch_bounds__(256) void la_k2(
    const float* __restrict__ x, const float* __restrict__ qin,
    const float* __restrict__ lepe_w, const float* __restrict__ lepe_b,
    const float* __restrict__ kv_g, const float* __restrict__ ksum_g,
    float* __restrict__ out)
{
  const int tid  = threadIdx.x;
  const int b    = blockIdx.x & 7;          // one batch per XCD for L2 locality
  const int seg  = blockIdx.x >> 3;         // 0..255: 64 tokens each
  const int lane = tid & 63;
  const int h    = __builtin_amdgcn_readfirstlane(tid >> 6);  // wave-uniform head
  const int token = seg * 64 + lane;
  const int xw   = token & 127;             // rope angle index + conv column
  const int y    = token >> 7;              // wave-uniform (64 | 128)

  __shared__ float theta_s[48];
  __shared__ float outs[64 * 100];          // 25 KB staging, pitch 100 f32
  if (tid < 48) theta_s[tid] = exp2f(-THETA_COEF * (float)tid);
  __syncthreads();

  const float inv_n = 1.0f / 16384.0f;

  float qv[24];
  const float* qp = qin + ((size_t)b * NLINE + token) * CCH + 24 * h;
#pragma unroll
  for (int t = 0; t < 6; ++t) {
    f32x4 v = ((const f32x4*)qp)[t];
    qv[4 * t] = v.x; qv[4 * t + 1] = v.y; qv[4 * t + 2] = v.z; qv[4 * t + 3] = v.w;
  }

  const float* km = ksum_g + b * 96 + 24 * h;
  float dot = 0.0f;
#pragma unroll
  for (int d2 = 0; d2 < 24; ++d2) dot += qv[d2] * km[d2];
  const float z = 1.0f / (dot * inv_n + 1e-6f);

  float qr[24];
#pragma unroll
  for (int jj = 0; jj < 12; ++jj) {
    float sn, cn;
    __sincosf((float)xw * theta_s[12 * h + jj], &sn, &cn);
    float re = qv[2 * jj], im = qv[2 * jj + 1];
    qr[2 * jj]     = re * cn - im * sn;
    qr[2 * jj + 1] = re * sn + im * cn;
  }

  const float* kvh = kv_g + ((size_t)b * 4 + h) * 576;
  float res[24];
#pragma unroll
  for (int e = 0; e < 24; ++e) res[e] = 0.0f;
  for (int d2 = 0; d2 < 24; ++d2) {
    float qd = qr[d2];
#pragma unroll
    for (int e = 0; e < 24; ++e) res[e] += qd * kvh[d2 * 24 + e];
  }
  const float* lb = lepe_b + 24 * h;
#pragma unroll
  for (int e = 0; e < 24; ++e) res[e] = res[e] * z + lb[e];

  // depthwise 3x3 conv straight from global x (f32, L2/L3-served)
  const float* lw = lepe_w + (size_t)(24 * h) * 9;
  const float* xbb = x + (size_t)b * NLINE * CCH;
#pragma unroll
  for (int dy = 0; dy < 3; ++dy) {
    int yy = y + dy - 1;
    if (yy < 0 || yy > 127) continue;       // wave-uniform
    const float* rowp = xbb + (size_t)yy * 128 * CCH;
#pragma unroll
    for (int dx = 0; dx < 3; ++dx) {
      int xx = xw + dx - 1;
      if (xx < 0 || xx > 127) continue;     // only edge lanes diverge
      const float* xp = rowp + xx * CCH + 24 * h;
      const int tap = dy * 3 + dx;
#pragma unroll
      for (int t = 0; t < 6; ++t) {
        f32x4 v = ((const f32x4*)xp)[t];
        res[4 * t]     += lw[(4 * t) * 9 + tap]     * v.x;
        res[4 * t + 1] += lw[(4 * t + 1) * 9 + tap] * v.y;
        res[4 * t + 2] += lw[(4 * t + 2) * 9 + tap] * v.z;
        res[4 * t + 3] += lw[(4 * t + 3) * 9 + tap] * v.w;
      }
    }
  }

#pragma unroll
  for (int t = 0; t < 6; ++t) {
    f32x4 v = { res[4 * t], res[4 * t + 1], res[4 * t + 2], res[4 * t + 3] };
    *(f32x4*)&outs[lane * 100 + 24 * h + 4 * t] = v;
  }
  __syncthreads();

  float* ob = out + ((size_t)b * NLINE + (size_t)seg * 64) * CCH;
  for (int i = tid; i < 1536; i += 256) {
    int tk = i / 24, c4 = i % 24;
    ((f32x4*)ob)[i] = *(const f32x4*)&outs[tk * 100 + c4 * 4];
  }
}

// ---------------------------------------------------------------- launch
extern "C" void kernel_launch(void* const* d_in, const int* in_sizes, int n_in,
                              void* d_out, int out_size, void* d_ws, size_t ws_size,
                              hipStream_t stream) {
  const float* x      = (const float*)d_in[0];
  const float* qkw    = (const float*)d_in[1];
  const float* qkb    = (const float*)d_in[2];
  const float* lepe_w = (const float*)d_in[3];
  const float* lepe_b = (const float*)d_in[4];
  float* out = (float*)d_out;

  unsigned short* wbf = (unsigned short*)d_ws;                 // 36864 B
  float* kv_g   = (float*)((char*)d_ws + 36864);               // 18432 f32
  float* ksum_g = kv_g + 18432;                                // 768 f32

  hipMemsetAsync(kv_g, 0, 19200 * sizeof(float), stream);
  prep_w<<<dim3(72), dim3(256), 0, stream>>>(qkw, wbf);
  la_k1<<<dim3(1024), dim3(256), 0, stream>>>(x, wbf, qkb, out, kv_g, ksum_g);
  la_k2<<<dim3(2048), dim3(256), 0, stream>>>(x, out, lepe_w, lepe_b, kv_g, ksum_g, out);
}

// Round 3
// 200.178 us; speedup vs baseline: 1.2512x; 1.0894x over previous
//
#include <hip/hip_runtime.h>

// LinearAttention: B=8, N=16384 (128x128), C=96, H=4, d=24
// prep: qk_w -> MFMA-fragment-ordered bf16 in ws (coalesced 1KB/wave frag loads)
// K1: k = elu(x@Wk^T+bk)+1 per 128-token line; ksum atomics; rope in transposed
//     LDS buffer; kv = K_rope^T V via MFMA -> global atomics.  (k-only)
// K2: per 64-token block: recompute q via MFMA GEMM (no q round-trip), then
//     rope/z/kv-matvec (wave-uniform s_load kv), then coalesced conv+store.

#define NLINE 16384
#define CCH 96
#define XSP 104    // x tile pitch (u16): 208B rows, 16B-aligned
#define KTP 136    // transposed k pitch (u16): 272B rows, 16B-aligned
#define QSP 98     // k2 q pitch (u16): 49-dword token stride -> conflict-free
#define OSP 97     // k2 out-staging pitch (f32): odd -> conflict-free
#define THETA_COEF 0.2768273412406135f  // log2(10000)/48

typedef __attribute__((ext_vector_type(4))) float f32x4;
typedef __attribute__((ext_vector_type(8))) short bf16x8;

__device__ __forceinline__ unsigned short f2bf(float f) {
  unsigned int u = __float_as_uint(f);
  u += 0x7FFFu + ((u >> 16) & 1u);          // RNE
  return (unsigned short)(u >> 16);
}
__device__ __forceinline__ float bf2f(unsigned short h) {
  return __uint_as_float(((unsigned int)h) << 16);
}
__device__ __forceinline__ void store_bf4(unsigned short* dst, f32x4 v) {
  unsigned long long pk = (unsigned long long)f2bf(v.x)
    | ((unsigned long long)f2bf(v.y) << 16)
    | ((unsigned long long)f2bf(v.z) << 32)
    | ((unsigned long long)f2bf(v.w) << 48);
  *(unsigned long long*)dst = pk;
}

// ---------------------------------------------------------------- prep
// wfrag uint4 index u = ((half*3+kk)*6+nt)*64 + lane ; lane = q4*16+lr
// holds W[half*96 + nt*16 + lr][kk*32 + q4*8 + j], j=0..7 as bf16x8.
__global__ void prep_w(const float* __restrict__ qkw, unsigned short* __restrict__ wfrag) {
  int u = blockIdx.x * 256 + threadIdx.x;
  if (u >= 2304) return;
  int lane = u & 63;
  int nt = (u >> 6) % 6;
  int rest = u / 384;           // half*3 + kk
  int kk = rest % 3, half = rest / 3;
  int lr = lane & 15, q4 = lane >> 4;
  int row = half * 96 + nt * 16 + lr;
  int col0 = kk * 32 + q4 * 8;
  const float* src = qkw + row * 96 + col0;
  unsigned short* dst = wfrag + (size_t)u * 8;
#pragma unroll
  for (int j = 0; j < 8; ++j) dst[j] = f2bf(src[j]);
}

// ---------------------------------------------------------------- kernel 1
__global__ __launch_bounds__(256, 3) void la_k1(
    const float* __restrict__ x, const unsigned short* __restrict__ wfrag,
    const float* __restrict__ qkb, float* __restrict__ kv_g,
    float* __restrict__ ksum_g)
{
  const int tid  = threadIdx.x;
  const int b    = blockIdx.x >> 7;
  const int tile = blockIdx.x & 127;        // = image line y; rope pos = row in tile

  __shared__ alignas(16) unsigned short xs[128 * XSP];   // 26624 B (v, bf16)
  __shared__ alignas(16) unsigned short kqt[96 * KTP];   // 26112 B (k transposed)
  __shared__ float theta_s[48];
  __shared__ float ksum_s[96];
  __shared__ float biask[96];

  if (tid < 96) { biask[tid] = qkb[96 + tid]; ksum_s[tid] = 0.0f; }
  if (tid < 48) theta_s[tid] = exp2f(-THETA_COEF * (float)tid);

  const float* xb = x + ((size_t)b * NLINE + (size_t)tile * 128) * CCH;
  for (int i = tid; i < 3072; i += 256) {
    int r = i / 24, c4 = i % 24;
    store_bf4(&xs[r * XSP + c4 * 4], ((const f32x4*)xb)[i]);
  }
  __syncthreads();

  const int wave = tid >> 6;
  const int lane = tid & 63;
  const int lr   = lane & 15;
  const int q4   = lane >> 4;
  const int row0 = wave * 32;

  // k = x @ Wk^T  (W fragments pre-shuffled: coalesced 1KB loads, L2-hot)
  f32x4 acc[2][6];
#pragma unroll
  for (int mt = 0; mt < 2; ++mt)
#pragma unroll
    for (int nt = 0; nt < 6; ++nt) acc[mt][nt] = (f32x4){0.f, 0.f, 0.f, 0.f};

#pragma unroll
  for (int kk = 0; kk < 3; ++kk) {
    const int koff = kk * 32 + q4 * 8;
    bf16x8 a0 = *(const bf16x8*)&xs[(row0 + lr) * XSP + koff];
    bf16x8 a1 = *(const bf16x8*)&xs[(row0 + 16 + lr) * XSP + koff];
#pragma unroll
    for (int nt = 0; nt < 6; ++nt) {
      bf16x8 bf = *(const bf16x8*)&wfrag[(size_t)(((3 + kk) * 6 + nt) * 64 + lane) * 8];
      acc[0][nt] = __builtin_amdgcn_mfma_f32_16x16x32_bf16(a0, bf, acc[0][nt], 0, 0, 0);
      acc[1][nt] = __builtin_amdgcn_mfma_f32_16x16x32_bf16(a1, bf, acc[1][nt], 0, 0, 0);
    }
  }

  // epilogue: +bias, elu+1, col-sums, store TRANSPOSED kqt[col*KTP + row]
#pragma unroll
  for (int nt = 0; nt < 6; ++nt) {
    const int col = nt * 16 + lr;
    const float bias = biask[col];
    float csum = 0.0f;
#pragma unroll
    for (int mt = 0; mt < 2; ++mt)
#pragma unroll
      for (int rg = 0; rg < 4; ++rg) {
        int row = row0 + mt * 16 + q4 * 4 + rg;
        float v = acc[mt][nt][rg] + bias;
        v = (v > 0.0f) ? (v + 1.0f) : __expf(v);
        csum += v;
        kqt[col * KTP + row] = f2bf(v);
      }
    atomicAdd(&ksum_s[col], csum);
  }
  __syncthreads();

  if (tid < 96) atomicAdd(&ksum_g[b * 96 + tid], ksum_s[tid]);

  // rope in transposed layout: pair cp=(0..47) -> cols (2cp, 2cp+1); pos = r
  for (int s = 0; s < 24; ++s) {
    int i = tid + 256 * s;
    int cp = i >> 7, r = i & 127;
    float re = bf2f(kqt[(2 * cp) * KTP + r]);
    float im = bf2f(kqt[(2 * cp + 1) * KTP + r]);
    float sn, cn;
    __sincosf((float)r * theta_s[cp], &sn, &cn);
    kqt[(2 * cp) * KTP + r]     = f2bf(re * cn - im * sn);
    kqt[(2 * cp + 1) * KTP + r] = f2bf(re * sn + im * cn);
  }
  __syncthreads();

  // kv: wave = head h: D[d][e] = sum_r k_rope[r][24h+d] * v[r][24h+e]
  const int h = wave;
  f32x4 kvacc[2][2];
#pragma unroll
  for (int mt = 0; mt < 2; ++mt)
#pragma unroll
    for (int nt = 0; nt < 2; ++nt) kvacc[mt][nt] = (f32x4){0.f, 0.f, 0.f, 0.f};

#pragma unroll
  for (int kk = 0; kk < 4; ++kk) {
    const int rbase = kk * 32 + q4 * 8;
    bf16x8 afr[2], bfr[2];
#pragma unroll
    for (int mt = 0; mt < 2; ++mt) {
      int c = 24 * h + mt * 16 + lr; if (c > 95) c = 95;   // garbage rows discarded
      afr[mt] = *(const bf16x8*)&kqt[c * KTP + rbase];     // aligned ds_read_b128
    }
#pragma unroll
    for (int nt = 0; nt < 2; ++nt) {
      int c = 24 * h + nt * 16 + lr; if (c > 95) c = 95;
#pragma unroll
      for (int j = 0; j < 8; ++j) bfr[nt][j] = (short)xs[(rbase + j) * XSP + c];
    }
#pragma unroll
    for (int mt = 0; mt < 2; ++mt)
#pragma unroll
      for (int nt = 0; nt < 2; ++nt)
        kvacc[mt][nt] = __builtin_amdgcn_mfma_f32_16x16x32_bf16(afr[mt], bfr[nt], kvacc[mt][nt], 0, 0, 0);
  }

  const float inv_n = 1.0f / 16384.0f;
  float* kvb = kv_g + ((size_t)b * 4 + h) * 576;
#pragma unroll
  for (int mt = 0; mt < 2; ++mt)
#pragma unroll
    for (int rg = 0; rg < 4; ++rg) {
      int d = mt * 16 + q4 * 4 + rg;
      if (d < 24) {
#pragma unroll
        for (int nt = 0; nt < 2; ++nt) {
          int e = nt * 16 + lr;
          if (e < 24) atomicAdd(&kvb[d * 24 + e], kvacc[mt][nt][rg] * inv_n);
        }
      }
    }
}

// ---------------------------------------------------------------- kernel 2
__global__ __launch_bounds__(256, 3) void la_k2(
    const float* __restrict__ x, const unsigned short* __restrict__ wfrag,
    const float* __restrict__ qkb, const float* __restrict__ lepe_w,
    const float* __restrict__ lepe_b, const float* __restrict__ kv_g,
    const float* __restrict__ ksum_g, float* __restrict__ out)
{
  const int tid = threadIdx.x;
  const int b   = blockIdx.x & 7;           // batch per XCD -> L2 locality
  const int seg = blockIdx.x >> 3;          // 64-token segment (half line)
  const int y   = seg >> 1;                 // image row (block-uniform)

  __shared__ alignas(16) unsigned short xs[64 * XSP];    // 13312 B
  __shared__ alignas(16) unsigned short qs[64 * QSP];    // 12544 B
  __shared__ float outs[64 * OSP];                       // 24832 B
  __shared__ float lepe_s[9 * 96];                       // 3456 B [tap][ch]
  __shared__ float theta_s[48];

  if (tid < 48) theta_s[tid] = exp2f(-THETA_COEF * (float)tid);
  for (int i = tid; i < 864; i += 256) {
    int ch = i / 9, tap = i % 9;
    lepe_s[tap * 96 + ch] = lepe_w[i];
  }

  // stage center 64 tokens of x -> bf16 LDS (coalesced)
  const float* xb = x + ((size_t)b * NLINE + (size_t)seg * 64) * CCH;
  for (int i = tid; i < 1536; i += 256) {
    int t = i / 24, c4 = i % 24;
    store_bf4(&xs[t * XSP + c4 * 4], ((const f32x4*)xb)[i]);
  }
  __syncthreads();

  const int wave = tid >> 6;
  const int lane = tid & 63;
  const int lr   = lane & 15;
  const int q4   = lane >> 4;

  // q-GEMM: wave handles rows 16w..16w+15
  f32x4 acc[6];
#pragma unroll
  for (int nt = 0; nt < 6; ++nt) acc[nt] = (f32x4){0.f, 0.f, 0.f, 0.f};
#pragma unroll
  for (int kk = 0; kk < 3; ++kk) {
    const int koff = kk * 32 + q4 * 8;
    bf16x8 a = *(const bf16x8*)&xs[(wave * 16 + lr) * XSP + koff];
#pragma unroll
    for (int nt = 0; nt < 6; ++nt) {
      bf16x8 bf = *(const bf16x8*)&wfrag[(size_t)((kk * 6 + nt) * 64 + lane) * 8];
      acc[nt] = __builtin_amdgcn_mfma_f32_16x16x32_bf16(a, bf, acc[nt], 0, 0, 0);
    }
  }
#pragma unroll
  for (int nt = 0; nt < 6; ++nt) {
    const int col = nt * 16 + lr;
    const float bias = qkb[col];
#pragma unroll
    for (int rg = 0; rg < 4; ++rg) {
      int t = wave * 16 + q4 * 4 + rg;
      float v = acc[nt][rg] + bias;
      v = (v > 0.0f) ? (v + 1.0f) : __expf(v);
      qs[t * QSP + col] = f2bf(v);
    }
  }
  __syncthreads();

  // phase A: (token, head) mapping; h wave-uniform -> kv/ksum via s_loads
  {
    const int t  = lane;
    const int h  = __builtin_amdgcn_readfirstlane(wave);
    const int xw = ((seg & 1) << 6) + t;
    const float inv_n = 1.0f / 16384.0f;

    float qv[24];
    const unsigned int* qrow = (const unsigned int*)&qs[t * QSP + 24 * h];
#pragma unroll
    for (int u = 0; u < 12; ++u) {
      unsigned int w = qrow[u];
      qv[2 * u]     = bf2f((unsigned short)(w & 0xFFFFu));
      qv[2 * u + 1] = bf2f((unsigned short)(w >> 16));
    }

    const float* km = ksum_g + b * 96 + 24 * h;
    float dot = 0.0f;
#pragma unroll
    for (int d2 = 0; d2 < 24; ++d2) dot += qv[d2] * km[d2];
    const float z = 1.0f / (dot * inv_n + 1e-6f);

    float qr[24];
#pragma unroll
    for (int jj = 0; jj < 12; ++jj) {
      float sn, cn;
      __sincosf((float)xw * theta_s[12 * h + jj], &sn, &cn);
      float re = qv[2 * jj], im = qv[2 * jj + 1];
      qr[2 * jj]     = re * cn - im * sn;
      qr[2 * jj + 1] = re * sn + im * cn;
    }

    const float* kvh = kv_g + ((size_t)b * 4 + h) * 576;
    float res[24];
#pragma unroll
    for (int e = 0; e < 24; ++e) res[e] = 0.0f;
    for (int d2 = 0; d2 < 24; ++d2) {
      float qd = qr[d2];
#pragma unroll
      for (int e = 0; e < 24; ++e) res[e] += qd * kvh[d2 * 24 + e];
    }
    const float* lb = lepe_b + 24 * h;
#pragma unroll
    for (int e = 0; e < 24; ++e) outs[t * OSP + 24 * h + e] = res[e] * z + lb[e];
  }
  __syncthreads();

  // phase B: (token, 4ch) mapping; coalesced conv reads + flat f32x4 stores
  float* ob = out + ((size_t)b * NLINE + (size_t)seg * 64) * CCH;
  const float* xg = x + (size_t)b * NLINE * CCH;
#pragma unroll
  for (int k = 0; k < 6; ++k) {
    int idx = tid + 256 * k;
    int tl = idx / 24, c4 = idx % 24;
    int ch0 = c4 * 4;
    int xw = ((seg & 1) << 6) + tl;

    float r0 = outs[tl * OSP + ch0];
    float r1 = outs[tl * OSP + ch0 + 1];
    float r2 = outs[tl * OSP + ch0 + 2];
    float r3 = outs[tl * OSP + ch0 + 3];

#pragma unroll
    for (int dy = 0; dy < 3; ++dy) {
      int yy = y + dy - 1;
      if (yy < 0 || yy > 127) continue;     // block-uniform
      const float* rowp = xg + ((size_t)yy * 128) * CCH;
#pragma unroll
      for (int dx = 0; dx < 3; ++dx) {
        int xx = xw + dx - 1;
        if (xx < 0 || xx > 127) continue;   // edge lanes only
        f32x4 v = *(const f32x4*)(rowp + xx * CCH + ch0);
        const int tap = dy * 3 + dx;
        const float* wp = &lepe_s[tap * 96 + ch0];
        r0 += wp[0] * v.x;
        r1 += wp[1] * v.y;
        r2 += wp[2] * v.z;
        r3 += wp[3] * v.w;
      }
    }
    f32x4 o = { r0, r1, r2, r3 };
    ((f32x4*)ob)[idx] = o;
  }
}

// ---------------------------------------------------------------- launch
extern "C" void kernel_launch(void* const* d_in, const int* in_sizes, int n_in,
                              void* d_out, int out_size, void* d_ws, size_t ws_size,
                              hipStream_t stream) {
  const float* x      = (const float*)d_in[0];
  const float* qkw    = (const float*)d_in[1];
  const float* qkb    = (const float*)d_in[2];
  const float* lepe_w = (const float*)d_in[3];
  const float* lepe_b = (const float*)d_in[4];
  float* out = (float*)d_out;

  unsigned short* wfrag = (unsigned short*)d_ws;            // 2304*16 = 36864 B
  float* kv_g   = (float*)((char*)d_ws + 36864);            // 18432 f32
  float* ksum_g = kv_g + 18432;                             // 768 f32

  hipMemsetAsync(kv_g, 0, 19200 * sizeof(float), stream);
  prep_w<<<dim3(9), dim3(256), 0, stream>>>(qkw, wfrag);
  la_k1<<<dim3(1024), dim3(256), 0, stream>>>(x, wfrag, qkb, kv_g, ksum_g);
  la_k2<<<dim3(2048), dim3(256), 0, stream>>>(x, wfrag, qkb, lepe_w, lepe_b, kv_g, ksum_g, out);
}

// Round 4
// 184.037 us; speedup vs baseline: 1.3610x; 1.0877x over previous
//
#include <hip/hip_runtime.h>

// LinearAttention: B=8, N=16384 (128x128), C=96, H=4, d=24
// prep: qk_w -> MFMA-fragment-ordered bf16 in ws
// K1 (3 blocks/CU): k-GEMM per line; ksum atomics; rope in transposed LDS;
//     kv = K_rope^T V via MFMA -> global atomics. xs XOR-swizzled.
// K2 (5 blocks/CU): q-GEMM with A-frags direct from global (no x staging),
//     rope/z/kv-matvec -> f16 LDS staging, coalesced conv+store.

#define NLINE 16384
#define CCH 96
#define XSP 104    // x tile pitch (u16)
#define KTP 136    // transposed k pitch (u16): 68 dwords/row -> 2-way banks
#define QSP 98     // k2 q pitch (u16)
#define OP2 100    // k2 out-staging pitch (f16)
#define THETA_COEF 0.2768273412406135f  // log2(10000)/48

typedef __attribute__((ext_vector_type(4))) float f32x4;
typedef __attribute__((ext_vector_type(8))) short bf16x8;

__device__ __forceinline__ unsigned short f2bf(float f) {
  unsigned int u = __float_as_uint(f);
  u += 0x7FFFu + ((u >> 16) & 1u);          // RNE
  return (unsigned short)(u >> 16);
}
__device__ __forceinline__ float bf2f(unsigned short h) {
  return __uint_as_float(((unsigned int)h) << 16);
}
__device__ __forceinline__ void store_bf4(unsigned short* dst, f32x4 v) {
  unsigned long long pk = (unsigned long long)f2bf(v.x)
    | ((unsigned long long)f2bf(v.y) << 16)
    | ((unsigned long long)f2bf(v.z) << 32)
    | ((unsigned long long)f2bf(v.w) << 48);
  *(unsigned long long*)dst = pk;
}

// ---------------------------------------------------------------- prep
// wfrag u = ((half*3+kk)*6+nt)*64 + lane holds W[half*96+nt*16+(lane&15)][kk*32+(lane>>4)*8 + 0..7]
__global__ void prep_w(const float* __restrict__ qkw, unsigned short* __restrict__ wfrag) {
  int u = blockIdx.x * 256 + threadIdx.x;
  if (u >= 2304) return;
  int lane = u & 63;
  int nt = (u >> 6) % 6;
  int rest = u / 384;
  int kk = rest % 3, half = rest / 3;
  int lr = lane & 15, q4 = lane >> 4;
  const float* src = qkw + (half * 96 + nt * 16 + lr) * 96 + kk * 32 + q4 * 8;
  unsigned short* dst = wfrag + (size_t)u * 8;
#pragma unroll
  for (int j = 0; j < 8; ++j) dst[j] = f2bf(src[j]);
}

// ---------------------------------------------------------------- kernel 1
__global__ __launch_bounds__(256, 3) void la_k1(
    const float* __restrict__ x, const unsigned short* __restrict__ wfrag,
    const float* __restrict__ qkb, float* __restrict__ kv_g,
    float* __restrict__ ksum_g)
{
  const int tid  = threadIdx.x;
  const int b    = blockIdx.x >> 7;
  const int tile = blockIdx.x & 127;        // image line y; rope pos = row in tile

  __shared__ alignas(16) unsigned short xs[128 * XSP];   // 26624 B (v, bf16, swizzled)
  __shared__ alignas(16) unsigned short kqt[96 * KTP];   // 26112 B (k transposed)
  __shared__ float ksum_s[96];                           // 384 B  -> 53.1 KB total

  if (tid < 96) ksum_s[tid] = 0.0f;

  const int wave = tid >> 6;
  const int lane = tid & 63;
  const int lr   = lane & 15;
  const int q4   = lane >> 4;
  const int row0 = wave * 32;

  // bias preload (global, L2-hot, hidden behind staging)
  float biasv[6];
#pragma unroll
  for (int nt = 0; nt < 6; ++nt) biasv[nt] = qkb[96 + nt * 16 + lr];

  // stage x tile bf16, group-swizzled: col-group g at position g ^ ((row>>3)&3)
  const float* xb = x + ((size_t)b * NLINE + (size_t)tile * 128) * CCH;
  for (int i = tid; i < 3072; i += 256) {
    int r = i / 24, c4 = i % 24;
    int sw = (r >> 3) & 3;
    store_bf4(&xs[r * XSP + ((((c4 >> 1) ^ sw) << 3) | ((c4 & 1) << 2))],
              ((const f32x4*)xb)[i]);
  }
  __syncthreads();

  // k = x @ Wk^T
  f32x4 acc[2][6];
#pragma unroll
  for (int mt = 0; mt < 2; ++mt)
#pragma unroll
    for (int nt = 0; nt < 6; ++nt) acc[mt][nt] = (f32x4){0.f, 0.f, 0.f, 0.f};

#pragma unroll
  for (int kk = 0; kk < 3; ++kk) {
    const int g = kk * 4 + q4;
    const int r1 = row0 + lr, r2 = row0 + 16 + lr;
    bf16x8 a0 = *(const bf16x8*)&xs[r1 * XSP + ((g ^ ((r1 >> 3) & 3)) << 3)];
    bf16x8 a1 = *(const bf16x8*)&xs[r2 * XSP + ((g ^ ((r2 >> 3) & 3)) << 3)];
#pragma unroll
    for (int nt = 0; nt < 6; ++nt) {
      bf16x8 bf = *(const bf16x8*)&wfrag[(size_t)(((3 + kk) * 6 + nt) * 64 + lane) * 8];
      acc[0][nt] = __builtin_amdgcn_mfma_f32_16x16x32_bf16(a0, bf, acc[0][nt], 0, 0, 0);
      acc[1][nt] = __builtin_amdgcn_mfma_f32_16x16x32_bf16(a1, bf, acc[1][nt], 0, 0, 0);
    }
  }

  // epilogue: +bias, elu+1, col-sums, store transposed kqt[col][row]
#pragma unroll
  for (int nt = 0; nt < 6; ++nt) {
    const int col = nt * 16 + lr;
    const float bias = biasv[nt];
    float csum = 0.0f;
#pragma unroll
    for (int mt = 0; mt < 2; ++mt)
#pragma unroll
      for (int rg = 0; rg < 4; ++rg) {
        int row = row0 + mt * 16 + q4 * 4 + rg;
        float v = acc[mt][nt][rg] + bias;
        v = (v > 0.0f) ? (v + 1.0f) : __expf(v);
        csum += v;
        kqt[col * KTP + row] = f2bf(v);
      }
    atomicAdd(&ksum_s[col], csum);
  }
  __syncthreads();

  if (tid < 96) atomicAdd(&ksum_g[b * 96 + tid], ksum_s[tid]);

  // rope in transposed layout: thread owns r = tid&127; cp = (tid>>7) + 2s
  {
    const int r = tid & 127;
    const int cp0 = tid >> 7;
    float theta = exp2f(-THETA_COEF * (float)cp0);
    const float fstep = exp2f(-2.0f * THETA_COEF);
#pragma unroll 4
    for (int s = 0; s < 24; ++s) {
      int cp = cp0 + 2 * s;
      float re = bf2f(kqt[(2 * cp) * KTP + r]);
      float im = bf2f(kqt[(2 * cp + 1) * KTP + r]);
      float sn, cn;
      __sincosf((float)r * theta, &sn, &cn);
      kqt[(2 * cp) * KTP + r]     = f2bf(re * cn - im * sn);
      kqt[(2 * cp + 1) * KTP + r] = f2bf(re * sn + im * cn);
      theta *= fstep;
    }
  }
  __syncthreads();

  // kv: wave = head h: D[d][e] = sum_r k_rope[r][24h+d] * v[r][24h+e]
  const int h = wave;
  f32x4 kvacc[2][2];
#pragma unroll
  for (int mt = 0; mt < 2; ++mt)
#pragma unroll
    for (int nt = 0; nt < 2; ++nt) kvacc[mt][nt] = (f32x4){0.f, 0.f, 0.f, 0.f};

#pragma unroll
  for (int kk = 0; kk < 4; ++kk) {
    const int rbase = kk * 32 + q4 * 8;
    const int sw = (rbase >> 3) & 3;
    bf16x8 afr[2], bfr[2];
#pragma unroll
    for (int mt = 0; mt < 2; ++mt) {
      int c = 24 * h + mt * 16 + lr; if (c > 95) c = 95;   // garbage rows discarded
      afr[mt] = *(const bf16x8*)&kqt[c * KTP + rbase];     // ds_read_b128
    }
#pragma unroll
    for (int nt = 0; nt < 2; ++nt) {
      int c = 24 * h + nt * 16 + lr; if (c > 95) c = 95;
      const int off = (((c >> 3) ^ sw) << 3) | (c & 7);
#pragma unroll
      for (int j = 0; j < 8; ++j) bfr[nt][j] = (short)xs[(rbase + j) * XSP + off];
    }
#pragma unroll
    for (int mt = 0; mt < 2; ++mt)
#pragma unroll
      for (int nt = 0; nt < 2; ++nt)
        kvacc[mt][nt] = __builtin_amdgcn_mfma_f32_16x16x32_bf16(afr[mt], bfr[nt], kvacc[mt][nt], 0, 0, 0);
  }

  const float inv_n = 1.0f / 16384.0f;
  float* kvb = kv_g + ((size_t)b * 4 + h) * 576;
#pragma unroll
  for (int mt = 0; mt < 2; ++mt)
#pragma unroll
    for (int rg = 0; rg < 4; ++rg) {
      int d = mt * 16 + q4 * 4 + rg;
      if (d < 24) {
#pragma unroll
        for (int nt = 0; nt < 2; ++nt) {
          int e = nt * 16 + lr;
          if (e < 24) atomicAdd(&kvb[d * 24 + e], kvacc[mt][nt][rg] * inv_n);
        }
      }
    }
}

// ---------------------------------------------------------------- kernel 2
__global__ __launch_bounds__(256, 5) void la_k2(
    const float* __restrict__ x, const unsigned short* __restrict__ wfrag,
    const float* __restrict__ qkb, const float* __restrict__ lepe_w,
    const float* __restrict__ lepe_b, const float* __restrict__ kv_g,
    const float* __restrict__ ksum_g, float* __restrict__ out)
{
  const int tid = threadIdx.x;
  const int b   = blockIdx.x & 7;           // batch per XCD -> L2 locality
  const int seg = blockIdx.x >> 3;          // 64-token segment (half line)
  const int y   = seg >> 1;                 // image row (block-uniform)

  __shared__ alignas(16) unsigned short qs[64 * QSP];    // 12544 B
  __shared__ _Float16 outs[64 * OP2];                    // 12800 B
  __shared__ float lepe_s[9 * 96];                       // 3456 B [tap][ch]
  __shared__ float theta_s[48];                          //  ~29 KB total

  if (tid < 48) theta_s[tid] = exp2f(-THETA_COEF * (float)tid);
  for (int i = tid; i < 864; i += 256) {
    int ch = i / 9, tap = i % 9;
    lepe_s[tap * 96 + ch] = lepe_w[i];
  }

  const int wave = tid >> 6;
  const int lane = tid & 63;
  const int lr   = lane & 15;
  const int q4   = lane >> 4;

  // bias preload
  float biasv[6];
#pragma unroll
  for (int nt = 0; nt < 6; ++nt) biasv[nt] = qkb[nt * 16 + lr];

  // A-fragments direct from global f32 (row = token handled by this wave)
  const float* xb = x + ((size_t)b * NLINE + (size_t)seg * 64) * CCH;
  bf16x8 afrag[3];
#pragma unroll
  for (int kk = 0; kk < 3; ++kk) {
    const float* ap = xb + (wave * 16 + lr) * CCH + kk * 32 + q4 * 8;
    f32x4 v0 = ((const f32x4*)ap)[0];
    f32x4 v1 = ((const f32x4*)ap)[1];
    afrag[kk][0] = (short)f2bf(v0.x); afrag[kk][1] = (short)f2bf(v0.y);
    afrag[kk][2] = (short)f2bf(v0.z); afrag[kk][3] = (short)f2bf(v0.w);
    afrag[kk][4] = (short)f2bf(v1.x); afrag[kk][5] = (short)f2bf(v1.y);
    afrag[kk][6] = (short)f2bf(v1.z); afrag[kk][7] = (short)f2bf(v1.w);
  }

  // q-GEMM: wave handles tokens 16w..16w+15
  f32x4 acc[6];
#pragma unroll
  for (int nt = 0; nt < 6; ++nt) acc[nt] = (f32x4){0.f, 0.f, 0.f, 0.f};
#pragma unroll
  for (int kk = 0; kk < 3; ++kk) {
#pragma unroll
    for (int nt = 0; nt < 6; ++nt) {
      bf16x8 bf = *(const bf16x8*)&wfrag[(size_t)((kk * 6 + nt) * 64 + lane) * 8];
      acc[nt] = __builtin_amdgcn_mfma_f32_16x16x32_bf16(afrag[kk], bf, acc[nt], 0, 0, 0);
    }
  }
#pragma unroll
  for (int nt = 0; nt < 6; ++nt) {
    const int col = nt * 16 + lr;
    const float bias = biasv[nt];
#pragma unroll
    for (int rg = 0; rg < 4; ++rg) {
      int t = wave * 16 + q4 * 4 + rg;
      float v = acc[nt][rg] + bias;
      v = (v > 0.0f) ? (v + 1.0f) : __expf(v);
      qs[t * QSP + col] = f2bf(v);
    }
  }
  __syncthreads();

  // phase A: (token, head); h wave-uniform -> kv/ksum scalarize to s_loads
  {
    const int t  = lane;
    const int h  = __builtin_amdgcn_readfirstlane(wave);
    const int xw = ((seg & 1) << 6) + t;
    const float inv_n = 1.0f / 16384.0f;

    float qv[24];
    const unsigned int* qrow = (const unsigned int*)&qs[t * QSP + 24 * h];
#pragma unroll
    for (int u = 0; u < 12; ++u) {
      unsigned int w = qrow[u];
      qv[2 * u]     = bf2f((unsigned short)(w & 0xFFFFu));
      qv[2 * u + 1] = bf2f((unsigned short)(w >> 16));
    }

    const float* km = ksum_g + b * 96 + 24 * h;
    float dot = 0.0f;
#pragma unroll
    for (int d2 = 0; d2 < 24; ++d2) dot += qv[d2] * km[d2];
    const float z = 1.0f / (dot * inv_n + 1e-6f);

    float qr[24];
#pragma unroll
    for (int jj = 0; jj < 12; ++jj) {
      float sn, cn;
      __sincosf((float)xw * theta_s[12 * h + jj], &sn, &cn);
      float re = qv[2 * jj], im = qv[2 * jj + 1];
      qr[2 * jj]     = re * cn - im * sn;
      qr[2 * jj + 1] = re * sn + im * cn;
    }

    const float* kvh = kv_g + ((size_t)b * 4 + h) * 576;
    float res[24];
#pragma unroll
    for (int e = 0; e < 24; ++e) res[e] = 0.0f;
    for (int d2 = 0; d2 < 24; ++d2) {
      float qd = qr[d2];
#pragma unroll
      for (int e = 0; e < 24; ++e) res[e] += qd * kvh[d2 * 24 + e];
    }
    const float* lb = lepe_b + 24 * h;
#pragma unroll
    for (int e = 0; e < 24; ++e)
      outs[t * OP2 + 24 * h + e] = (_Float16)(res[e] * z + lb[e]);
  }
  __syncthreads();

  // phase B: (token, 4ch); coalesced conv reads + flat f32x4 stores
  float* ob = out + ((size_t)b * NLINE + (size_t)seg * 64) * CCH;
  const float* xg = x + (size_t)b * NLINE * CCH;
#pragma unroll
  for (int k = 0; k < 6; ++k) {
    int idx = tid + 256 * k;
    int tl = idx / 24, c4 = idx % 24;
    int ch0 = c4 * 4;
    int xw = ((seg & 1) << 6) + tl;

    float r0 = (float)outs[tl * OP2 + ch0];
    float r1 = (float)outs[tl * OP2 + ch0 + 1];
    float r2 = (float)outs[tl * OP2 + ch0 + 2];
    float r3 = (float)outs[tl * OP2 + ch0 + 3];

#pragma unroll
    for (int dy = 0; dy < 3; ++dy) {
      int yy = y + dy - 1;
      if (yy < 0 || yy > 127) continue;     // block-uniform
      const float* rowp = xg + ((size_t)yy * 128) * CCH;
#pragma unroll
      for (int dx = 0; dx < 3; ++dx) {
        int xx = xw + dx - 1;
        if (xx < 0 || xx > 127) continue;   // edge lanes only
        f32x4 v = *(const f32x4*)(rowp + xx * CCH + ch0);
        const float* wp = &lepe_s[(dy * 3 + dx) * 96 + ch0];
        r0 += wp[0] * v.x;
        r1 += wp[1] * v.y;
        r2 += wp[2] * v.z;
        r3 += wp[3] * v.w;
      }
    }
    f32x4 o = { r0, r1, r2, r3 };
    ((f32x4*)ob)[idx] = o;
  }
}

// ---------------------------------------------------------------- launch
extern "C" void kernel_launch(void* const* d_in, const int* in_sizes, int n_in,
                              void* d_out, int out_size, void* d_ws, size_t ws_size,
                              hipStream_t stream) {
  const float* x      = (const float*)d_in[0];
  const float* qkw    = (const float*)d_in[1];
  const float* qkb    = (const float*)d_in[2];
  const float* lepe_w = (const float*)d_in[3];
  const float* lepe_b = (const float*)d_in[4];
  float* out = (float*)d_out;

  unsigned short* wfrag = (unsigned short*)d_ws;            // 36864 B
  float* kv_g   = (float*)((char*)d_ws + 36864);            // 18432 f32
  float* ksum_g = kv_g + 18432;                             // 768 f32

  hipMemsetAsync(kv_g, 0, 19200 * sizeof(float), stream);
  prep_w<<<dim3(9), dim3(256), 0, stream>>>(qkw, wfrag);
  la_k1<<<dim3(1024), dim3(256), 0, stream>>>(x, wfrag, qkb, kv_g, ksum_g);
  la_k2<<<dim3(2048), dim3(256), 0, stream>>>(x, wfrag, qkb, lepe_w, lepe_b, kv_g, ksum_g, out);
}

// Round 6
// 175.750 us; speedup vs baseline: 1.4251x; 1.0472x over previous
//
#include <hip/hip_runtime.h>

// LinearAttention: B=8, N=16384 (128x128), C=96, H=4, d=24
// prep: qk_w -> MFMA-fragment-ordered bf16 in ws
// K1 (no x staging, 26.5KB LDS): k-GEMM with A-frags direct from global;
//     in-register rope (v_sin) + b64 transposed kqt writes; kv = K_rope^T V
//     via MFMA (A from kqt b128, V direct from global) -> global atomics.
// K2 (15.6KB LDS, 8 blocks/CU): q-GEMM direct-from-global A-frags; phase A
//     rope/z/kv-matvec in regs; qs buffer reused as f16 out staging; conv+store.

#define NLINE 16384
#define CCH 96
#define KTP 136    // transposed k pitch (u16): 272B rows (16B-mult)
#define QSP 98     // k2 q pitch (u16)
#define THETA_COEF 0.2768273412406135f   // log2(10000)/48
#define LOG2_2PI   2.6514961294723187f   // log2(2*pi)

typedef __attribute__((ext_vector_type(4))) float f32x4;
typedef __attribute__((ext_vector_type(8))) short bf16x8;
typedef __attribute__((ext_vector_type(2))) __fp16 fp16x2;

__device__ __forceinline__ unsigned short f2bf(float f) {
  unsigned int u = __float_as_uint(f);
  u += 0x7FFFu + ((u >> 16) & 1u);          // RNE
  return (unsigned short)(u >> 16);
}
__device__ __forceinline__ float bf2f(unsigned short h) {
  return __uint_as_float(((unsigned int)h) << 16);
}
__device__ __forceinline__ bf16x8 pack_bf8(f32x4 v0, f32x4 v1) {
  bf16x8 r;
  r[0] = (short)f2bf(v0.x); r[1] = (short)f2bf(v0.y);
  r[2] = (short)f2bf(v0.z); r[3] = (short)f2bf(v0.w);
  r[4] = (short)f2bf(v1.x); r[5] = (short)f2bf(v1.y);
  r[6] = (short)f2bf(v1.z); r[7] = (short)f2bf(v1.w);
  return r;
}

// ---------------------------------------------------------------- prep
// wfrag u = ((half*3+kk)*6+nt)*64 + lane holds W[half*96+nt*16+(lane&15)][kk*32+(lane>>4)*8 + 0..7]
__global__ void prep_w(const float* __restrict__ qkw, unsigned short* __restrict__ wfrag) {
  int u = blockIdx.x * 256 + threadIdx.x;
  if (u >= 2304) return;
  int lane = u & 63;
  int nt = (u >> 6) % 6;
  int rest = u / 384;
  int kk = rest % 3, half = rest / 3;
  int lr = lane & 15, q4 = lane >> 4;
  const float* src = qkw + (half * 96 + nt * 16 + lr) * 96 + kk * 32 + q4 * 8;
  unsigned short* dst = wfrag + (size_t)u * 8;
#pragma unroll
  for (int j = 0; j < 8; ++j) dst[j] = f2bf(src[j]);
}

// ---------------------------------------------------------------- kernel 1
__global__ __launch_bounds__(256, 4) void la_k1(
    const float* __restrict__ x, const unsigned short* __restrict__ wfrag,
    const float* __restrict__ qkb, float* __restrict__ kv_g,
    float* __restrict__ ksum_g)
{
  const int tid  = threadIdx.x;
  const int b    = blockIdx.x >> 7;
  const int tile = blockIdx.x & 127;        // image line y; rope pos = row in tile

  __shared__ alignas(16) unsigned short kqt[96 * KTP];   // 26112 B (k_rope transposed)
  __shared__ float ksum_s[96];

  if (tid < 96) ksum_s[tid] = 0.0f;
  __syncthreads();                          // init vs epilogue atomics

  const int wave = tid >> 6;
  const int lane = tid & 63;
  const int lr   = lane & 15;
  const int q4   = lane >> 4;
  const int row0 = wave * 32;
  const float* xb = x + ((size_t)b * NLINE + (size_t)tile * 128) * CCH;

  // A-fragments direct from global f32 (16 rows x 128B segments per pair)
  bf16x8 afr[2][3];
#pragma unroll
  for (int mt = 0; mt < 2; ++mt)
#pragma unroll
    for (int kk = 0; kk < 3; ++kk) {
      const float* ap = xb + (row0 + mt * 16 + lr) * CCH + kk * 32 + q4 * 8;
      afr[mt][kk] = pack_bf8(((const f32x4*)ap)[0], ((const f32x4*)ap)[1]);
    }

  float biasv[6];
#pragma unroll
  for (int nt = 0; nt < 6; ++nt) biasv[nt] = qkb[96 + nt * 16 + lr];

  // k = x @ Wk^T
  f32x4 acc[2][6];
#pragma unroll
  for (int mt = 0; mt < 2; ++mt)
#pragma unroll
    for (int nt = 0; nt < 6; ++nt) acc[mt][nt] = (f32x4){0.f, 0.f, 0.f, 0.f};

#pragma unroll
  for (int kk = 0; kk < 3; ++kk) {
#pragma unroll
    for (int nt = 0; nt < 6; ++nt) {
      bf16x8 bf = *(const bf16x8*)&wfrag[(size_t)(((3 + kk) * 6 + nt) * 64 + lane) * 8];
      acc[0][nt] = __builtin_amdgcn_mfma_f32_16x16x32_bf16(afr[0][kk], bf, acc[0][nt], 0, 0, 0);
      acc[1][nt] = __builtin_amdgcn_mfma_f32_16x16x32_bf16(afr[1][kk], bf, acc[1][nt], 0, 0, 0);
    }
  }

  // epilogue: bias+elu+1, col-sums, in-register rope, packed b64 transposed store
  const int odd = lr & 1;
#pragma unroll
  for (int nt = 0; nt < 6; ++nt) {
    const int col = nt * 16 + lr;
    const float threv = exp2f(-THETA_COEF * (float)(col >> 1) - LOG2_2PI); // theta/(2pi)
    float csum = 0.0f;
    float vv[2][4];
#pragma unroll
    for (int mt = 0; mt < 2; ++mt)
#pragma unroll
      for (int rg = 0; rg < 4; ++rg) {
        float v = acc[mt][nt][rg] + biasv[nt];
        v = (v > 0.0f) ? (v + 1.0f) : __expf(v);   // elu+1
        csum += v;
        vv[mt][rg] = v;
      }
    atomicAdd(&ksum_s[col], csum);                 // ksum over NON-roped k
#pragma unroll
    for (int mt = 0; mt < 2; ++mt) {
      unsigned long long pk = 0;
#pragma unroll
      for (int rg = 0; rg < 4; ++rg) {
        float p = __shfl_xor(vv[mt][rg], 1);       // partner col (re<->im)
        int r = row0 + mt * 16 + q4 * 4 + rg;
        float rev = (float)r * threv;
        float sn = __builtin_amdgcn_sinf(rev);     // sin(2*pi*rev) = sin(r*theta)
        float cn = __builtin_amdgcn_cosf(rev);
        float o = odd ? (p * sn + vv[mt][rg] * cn)
                      : (vv[mt][rg] * cn - p * sn);
        pk |= (unsigned long long)f2bf(o) << (16 * rg);
      }
      *(unsigned long long*)&kqt[col * KTP + row0 + mt * 16 + q4 * 4] = pk;
    }
  }
  __syncthreads();

  if (tid < 96) atomicAdd(&ksum_g[b * 96 + tid], ksum_s[tid]);

  // kv: wave = head h: D[d][e] = sum_r k_rope[r][24h+d] * v[r][24h+e]
  const int h = wave;
  f32x4 kvacc[2][2];
#pragma unroll
  for (int mt = 0; mt < 2; ++mt)
#pragma unroll
    for (int nt = 0; nt < 2; ++nt) kvacc[mt][nt] = (f32x4){0.f, 0.f, 0.f, 0.f};

#pragma unroll
  for (int kk = 0; kk < 4; ++kk) {
    const int rbase = kk * 32 + q4 * 8;
    bf16x8 ka[2], vb[2];
#pragma unroll
    for (int mt = 0; mt < 2; ++mt) {
      int c = 24 * h + mt * 16 + lr; if (c > 95) c = 95;   // garbage cells discarded
      ka[mt] = *(const bf16x8*)&kqt[c * KTP + rbase];      // aligned ds_read_b128
    }
#pragma unroll
    for (int nt = 0; nt < 2; ++nt) {
      int c = 24 * h + nt * 16 + lr; if (c > 95) c = 95;
#pragma unroll
      for (int j = 0; j < 8; ++j)
        vb[nt][j] = (short)f2bf(xb[(rbase + j) * CCH + c]);  // V direct from global (L2-hot)
    }
#pragma unroll
    for (int mt = 0; mt < 2; ++mt)
#pragma unroll
      for (int nt = 0; nt < 2; ++nt)
        kvacc[mt][nt] = __builtin_amdgcn_mfma_f32_16x16x32_bf16(ka[mt], vb[nt], kvacc[mt][nt], 0, 0, 0);
  }

  const float inv_n = 1.0f / 16384.0f;
  float* kvb = kv_g + ((size_t)b * 4 + h) * 576;
#pragma unroll
  for (int mt = 0; mt < 2; ++mt)
#pragma unroll
    for (int rg = 0; rg < 4; ++rg) {
      int d = mt * 16 + q4 * 4 + rg;
      if (d < 24) {
#pragma unroll
        for (int nt = 0; nt < 2; ++nt) {
          int e = nt * 16 + lr;
          if (e < 24) atomicAdd(&kvb[d * 24 + e], kvacc[mt][nt][rg] * inv_n);
        }
      }
    }
}

// ---------------------------------------------------------------- kernel 2
__global__ __launch_bounds__(256, 8) void la_k2(
    const float* __restrict__ x, const unsigned short* __restrict__ wfrag,
    const float* __restrict__ qkb, const float* __restrict__ lepe_w,
    const float* __restrict__ lepe_b, const float* __restrict__ kv_g,
    const float* __restrict__ ksum_g, float* __restrict__ out)
{
  const int tid = threadIdx.x;
  const int b   = blockIdx.x & 7;           // batch per XCD -> L2 locality
  const int seg = blockIdx.x >> 3;          // 64-token segment (half line)
  const int y   = seg >> 1;                 // image row (block-uniform)

  __shared__ alignas(16) unsigned short qs[64 * QSP];    // 12544 B; reused as f16 outs
  __shared__ float lepe_s[9 * 96];                       // 3456 B [tap][ch]

  for (int i = tid; i < 864; i += 256) {
    int ch = i / 9, tap = i % 9;
    lepe_s[tap * 96 + ch] = lepe_w[i];
  }

  const int wave = tid >> 6;
  const int lane = tid & 63;
  const int lr   = lane & 15;
  const int q4   = lane >> 4;

  float biasv[6];
#pragma unroll
  for (int nt = 0; nt < 6; ++nt) biasv[nt] = qkb[nt * 16 + lr];

  // A-fragments direct from global f32
  const float* xb = x + ((size_t)b * NLINE + (size_t)seg * 64) * CCH;
  bf16x8 afrag[3];
#pragma unroll
  for (int kk = 0; kk < 3; ++kk) {
    const float* ap = xb + (wave * 16 + lr) * CCH + kk * 32 + q4 * 8;
    afrag[kk] = pack_bf8(((const f32x4*)ap)[0], ((const f32x4*)ap)[1]);
  }

  // q-GEMM: wave handles tokens 16w..16w+15
  f32x4 acc[6];
#pragma unroll
  for (int nt = 0; nt < 6; ++nt) acc[nt] = (f32x4){0.f, 0.f, 0.f, 0.f};
#pragma unroll
  for (int kk = 0; kk < 3; ++kk) {
#pragma unroll
    for (int nt = 0; nt < 6; ++nt) {
      bf16x8 bf = *(const bf16x8*)&wfrag[(size_t)((kk * 6 + nt) * 64 + lane) * 8];
      acc[nt] = __builtin_amdgcn_mfma_f32_16x16x32_bf16(afrag[kk], bf, acc[nt], 0, 0, 0);
    }
  }
#pragma unroll
  for (int nt = 0; nt < 6; ++nt) {
    const int col = nt * 16 + lr;
#pragma unroll
    for (int rg = 0; rg < 4; ++rg) {
      int t = wave * 16 + q4 * 4 + rg;
      float v = acc[nt][rg] + biasv[nt];
      v = (v > 0.0f) ? (v + 1.0f) : __expf(v);
      qs[t * QSP + col] = f2bf(v);
    }
  }
  __syncthreads();

  // phase A: (token=lane, head=wave); h wave-uniform -> kv/ksum scalarize
  float res[24];
  {
    const int t  = lane;
    const int h  = __builtin_amdgcn_readfirstlane(wave);
    const int xw = ((seg & 1) << 6) + t;
    const float inv_n = 1.0f / 16384.0f;

    float qv[24];
    const unsigned int* qrow = (const unsigned int*)&qs[t * QSP + 24 * h];
#pragma unroll
    for (int u = 0; u < 12; ++u) {
      unsigned int w = qrow[u];
      qv[2 * u]     = bf2f((unsigned short)(w & 0xFFFFu));
      qv[2 * u + 1] = bf2f((unsigned short)(w >> 16));
    }

    const float* km = ksum_g + b * 96 + 24 * h;
    float dot = 0.0f;
#pragma unroll
    for (int d2 = 0; d2 < 24; ++d2) dot += qv[d2] * km[d2];   // pre-rope q
    const float z = 1.0f / (dot * inv_n + 1e-6f);

    // in-place rope on qv (v_sin/v_cos, revolutions)
#pragma unroll
    for (int jj = 0; jj < 12; ++jj) {
      float threv = exp2f(-THETA_COEF * (float)(12 * h + jj) - LOG2_2PI);
      float rev = (float)xw * threv;
      float sn = __builtin_amdgcn_sinf(rev);
      float cn = __builtin_amdgcn_cosf(rev);
      float re = qv[2 * jj], im = qv[2 * jj + 1];
      qv[2 * jj]     = re * cn - im * sn;
      qv[2 * jj + 1] = re * sn + im * cn;
    }

    const float* kvh = kv_g + ((size_t)b * 4 + h) * 576;
#pragma unroll
    for (int e = 0; e < 24; ++e) res[e] = 0.0f;
    for (int d2 = 0; d2 < 24; ++d2) {
      float qd = qv[d2];
#pragma unroll
      for (int e = 0; e < 24; ++e) res[e] += qd * kvh[d2 * 24 + e];
    }
    const float* lb = lepe_b + 24 * h;
#pragma unroll
    for (int e = 0; e < 24; ++e) res[e] = res[e] * z + lb[e];
  }
  __syncthreads();                          // all qs reads done

  // stage res -> f16 in the qs buffer (pitch 96, 12288 B <= 12544 B)
  __fp16* outs = (__fp16*)qs;
  {
    const int t = lane;
    const int h = wave;
#pragma unroll
    for (int u = 0; u < 12; ++u) {
      fp16x2 pk = __builtin_amdgcn_cvt_pkrtz(res[2 * u], res[2 * u + 1]);
      *(fp16x2*)&outs[t * 96 + 24 * h + 2 * u] = pk;
    }
  }
  __syncthreads();

  // phase B: (token, 4ch); coalesced conv reads + flat f32x4 stores
  float* ob = out + ((size_t)b * NLINE + (size_t)seg * 64) * CCH;
  const float* xg = x + (size_t)b * NLINE * CCH;
#pragma unroll
  for (int k = 0; k < 6; ++k) {
    int idx = tid + 256 * k;
    int tl = idx / 24, c4 = idx % 24;
    int ch0 = c4 * 4;
    int xw = ((seg & 1) << 6) + tl;

    fp16x2 p0 = *(const fp16x2*)&outs[tl * 96 + ch0];
    fp16x2 p1 = *(const fp16x2*)&outs[tl * 96 + ch0 + 2];
    float r0 = (float)p0[0], r1 = (float)p0[1];
    float r2 = (float)p1[0], r3 = (float)p1[1];

#pragma unroll
    for (int dy = 0; dy < 3; ++dy) {
      int yy = y + dy - 1;
      if (yy < 0 || yy > 127) continue;     // block-uniform
      const float* rowp = xg + ((size_t)yy * 128) * CCH;
#pragma unroll
      for (int dx = 0; dx < 3; ++dx) {
        int xx = xw + dx - 1;
        if (xx < 0 || xx > 127) continue;   // edge lanes only
        f32x4 v = *(const f32x4*)(rowp + xx * CCH + ch0);
        const float* wp = &lepe_s[(dy * 3 + dx) * 96 + ch0];
        r0 += wp[0] * v.x;
        r1 += wp[1] * v.y;
        r2 += wp[2] * v.z;
        r3 += wp[3] * v.w;
      }
    }
    f32x4 o = { r0, r1, r2, r3 };
    ((f32x4*)ob)[idx] = o;
  }
}

// ---------------------------------------------------------------- launch
extern "C" void kernel_launch(void* const* d_in, const int* in_sizes, int n_in,
                              void* d_out, int out_size, void* d_ws, size_t ws_size,
                              hipStream_t stream) {
  const float* x      = (const float*)d_in[0];
  const float* qkw    = (const float*)d_in[1];
  const float* qkb    = (const float*)d_in[2];
  const float* lepe_w = (const float*)d_in[3];
  const float* lepe_b = (const float*)d_in[4];
  float* out = (float*)d_out;

  unsigned short* wfrag = (unsigned short*)d_ws;            // 36864 B
  float* kv_g   = (float*)((char*)d_ws + 36864);            // 18432 f32
  float* ksum_g = kv_g + 18432;                             // 768 f32

  (void)hipMemsetAsync(kv_g, 0, 19200 * sizeof(float), stream);
  prep_w<<<dim3(9), dim3(256), 0, stream>>>(qkw, wfrag);
  la_k1<<<dim3(1024), dim3(256), 0, stream>>>(x, wfrag, qkb, kv_g, ksum_g);
  la_k2<<<dim3(2048), dim3(256), 0, stream>>>(x, wfrag, qkb, lepe_w, lepe_b, kv_g, ksum_g, out);
}